// Round 18
// baseline (131.442 us; speedup 1.0000x reference)
//
#include <hip/hip_runtime.h>
#include <hip/hip_bf16.h>
#include <stdint.h>

#define NN 8192
#define DIN 256
#define HID 128
#define SCALE 0.08838834764831845f  // 1/(sqrt(128)*1.0)

typedef __attribute__((ext_vector_type(8))) short short8;
typedef __attribute__((ext_vector_type(4))) float f32x4;
typedef __attribute__((ext_vector_type(16))) float f32x16;
typedef __attribute__((ext_vector_type(8))) unsigned short u16x8;
typedef __attribute__((ext_vector_type(4))) unsigned int u32x4;

__device__ __forceinline__ unsigned short f2bf(float f) {
  unsigned int u = __builtin_bit_cast(unsigned int, f);
  u += 0x7FFFu + ((u >> 16) & 1u);   // round-to-nearest-even
  return (unsigned short)(u >> 16);
}

__device__ __forceinline__ unsigned int cvtpk(float lo, float hi) {
  unsigned int r;
  asm("v_cvt_pk_bf16_f32 %0, %1, %2" : "=v"(r) : "v"(lo), "v"(hi));
  return r;
}

__device__ __forceinline__ void async16(const void* g, void* l) {
  __builtin_amdgcn_global_load_lds(
      (const __attribute__((address_space(1))) unsigned int*)g,
      (__attribute__((address_space(3))) unsigned int*)l, 16, 0, 0);
}

// ---------------- Kernel W: weights -> bf16 transposed ----------------
__global__ __launch_bounds__(256) void kw0(
    const float* __restrict__ msg_w, const float* __restrict__ qw,
    const float* __restrict__ kw, const float* __restrict__ upd_w,
    unsigned short* __restrict__ mwT, unsigned short* __restrict__ qwT,
    unsigned short* __restrict__ kwT, unsigned short* __restrict__ w_t) {
  int idx0 = blockIdx.x * 1792 + threadIdx.x;
#pragma unroll
  for (int it = 0; it < 7; ++it) {
    int idx = idx0 + it * 256;
    if (idx < 32768) {                       // mwT
      int h = idx >> 8, j = idx & 255;
      mwT[idx] = f2bf(msg_w[j * HID + h]);
    } else if (idx < 49152) {                // qwT
      int r = idx - 32768, h = r >> 7, j = r & 127;
      qwT[r] = f2bf(qw[j * HID + h]);
    } else if (idx < 65536) {                // kwT
      int r = idx - 49152, h = r >> 7, j = r & 127;
      kwT[r] = f2bf(kw[j * HID + h]);
    } else {                                 // w_t
      int r = idx - 65536, h = r / 384, j = r % 384;
      w_t[r] = f2bf(upd_w[j * HID + h]);
    }
  }
}

// ---------------- Kernel A: messages, q, k via MFMA ----------------
// k_bf fragment-major: element k[j][kd] ->
//   ((j>>5)*8 + (kd>>4))*512 + (((kd>>3)&1)*32 + (j&31))*8 + (kd&7)
// m_t  fragment-major: element mT[h][j] ->
//   ((j>>4)*4 + (h>>5))*512 + (((j>>3)&1)*32 + (h&31))*8 + (j&7)
__global__ __launch_bounds__(256) void ka(
    const float* __restrict__ nf, const unsigned short* __restrict__ mwT,
    const float* __restrict__ msg_b, const unsigned short* __restrict__ qwT,
    const unsigned short* __restrict__ kwT, unsigned short* __restrict__ q_bf,
    unsigned short* __restrict__ k_bf, unsigned short* __restrict__ m_t,
    unsigned short* __restrict__ nf_bf) {
  __shared__ __align__(16) unsigned short nfl[32][264];
  __shared__ __align__(16) unsigned short ml[32][136];
  int t = threadIdx.x, l = t & 63, w = t >> 6;
  int lr = l & 15, lg = l >> 4;
  int i0 = blockIdx.x * 32;
  {
    int row = t >> 3, c0 = (t & 7) * 32;
    const float* src = nf + (size_t)(i0 + row) * DIN + c0;
    unsigned short* gdst = nf_bf + (size_t)(i0 + row) * DIN + c0;
#pragma unroll
    for (int v = 0; v < 4; ++v) {
      f32x4 a = *(const f32x4*)(src + v * 8);
      f32x4 b = *(const f32x4*)(src + v * 8 + 4);
      u16x8 o;
#pragma unroll
      for (int e = 0; e < 4; ++e) { o[e] = f2bf(a[e]); o[4 + e] = f2bf(b[e]); }
      *(u16x8*)&nfl[row][c0 + v * 8] = o;
      *(u16x8*)(gdst + v * 8) = o;
    }
  }
  __syncthreads();
  int rl = (w >> 1) * 16;
  int nb = (w & 1) * 4;
  f32x4 macc[4];
#pragma unroll
  for (int nt = 0; nt < 4; ++nt) macc[nt] = (f32x4){0.f, 0.f, 0.f, 0.f};
#pragma unroll
  for (int kk = 0; kk < 8; ++kk) {
    short8 af = *(const short8*)&nfl[rl + lr][kk * 32 + lg * 8];
#pragma unroll
    for (int nt = 0; nt < 4; ++nt) {
      short8 bf = *(const short8*)(mwT + (size_t)((nb + nt) * 16 + lr) * DIN + kk * 32 + lg * 8);
      macc[nt] = __builtin_amdgcn_mfma_f32_16x16x32_bf16(af, bf, macc[nt], 0, 0, 0);
    }
  }
#pragma unroll
  for (int nt = 0; nt < 4; ++nt) {
    int col = (nb + nt) * 16 + lr;
    float bias = msg_b[col];
#pragma unroll
    for (int reg = 0; reg < 4; ++reg)
      ml[rl + lg * 4 + reg][col] = f2bf(macc[nt][reg] + bias);
  }
  __syncthreads();
  // m_t writeout: fragment-major
  {
    int hh = t >> 1;
    int Ibase = (t & 1) * 16;
    int I = i0 + Ibase;   // 16-aligned
    unsigned short* mb =
        m_t + ((size_t)(I >> 4) * 4 + (hh >> 5)) * 512 + (hh & 31) * 8;
    u16x8 o0, o1;
#pragma unroll
    for (int v = 0; v < 8; ++v) {
      o0[v] = ml[Ibase + v][hh];
      o1[v] = ml[Ibase + 8 + v][hh];
    }
    *(u16x8*)(mb) = o0;          // j-bit3 = 0 -> lane 0..31 side
    *(u16x8*)(mb + 256) = o1;    // j-bit3 = 1 -> lane 32..63 side
  }
  f32x4 qacc[4], kacc[4];
#pragma unroll
  for (int nt = 0; nt < 4; ++nt) {
    qacc[nt] = (f32x4){0.f, 0.f, 0.f, 0.f};
    kacc[nt] = (f32x4){0.f, 0.f, 0.f, 0.f};
  }
#pragma unroll
  for (int kk = 0; kk < 4; ++kk) {
    short8 af = *(const short8*)&ml[rl + lr][kk * 32 + lg * 8];
#pragma unroll
    for (int nt = 0; nt < 4; ++nt) {
      short8 bq = *(const short8*)(qwT + (size_t)((nb + nt) * 16 + lr) * HID + kk * 32 + lg * 8);
      short8 bk = *(const short8*)(kwT + (size_t)((nb + nt) * 16 + lr) * HID + kk * 32 + lg * 8);
      qacc[nt] = __builtin_amdgcn_mfma_f32_16x16x32_bf16(af, bq, qacc[nt], 0, 0, 0);
      kacc[nt] = __builtin_amdgcn_mfma_f32_16x16x32_bf16(af, bk, kacc[nt], 0, 0, 0);
    }
  }
#pragma unroll
  for (int nt = 0; nt < 4; ++nt) {
    int col = (nb + nt) * 16 + lr;        // kd for k, h for q
#pragma unroll
    for (int reg = 0; reg < 4; ++reg) {
      int row = i0 + rl + lg * 4 + reg;   // node index
      q_bf[(size_t)row * HID + col] = f2bf(qacc[nt][reg]);
      size_t ko = ((size_t)(row >> 5) * 8 + (col >> 4)) * 512 +
                  (((col >> 3) & 1) * 32 + (row & 31)) * 8 + (col & 7);
      k_bf[ko] = f2bf(kacc[nt][reg]);
    }
  }
}

// ---------------- Kernel B: fused gate + aggregate, 128-j staging ----------------
// R16 champion with ONE change: staging granularity 64-j -> 128-j tiles
// (64 KB per stage). Halves barrier crossings (32 -> 16 per block) and gives
// the global_load_lds queue deeper bursts per drain. LDS 2x64 KB = 128 KB ->
// still exactly 2 blocks/CU (16 waves), same VGPR, same staged bytes, same
// arithmetic order. Wave (ig = w&3, hg = w>>2); hg pair redundantly
// recomputes QK+gate.
__global__ __launch_bounds__(512, 4) void kb(
    const unsigned short* __restrict__ q_bf, const unsigned short* __restrict__ k_bf,
    const unsigned short* __restrict__ m_t, const float* __restrict__ adj,
    const float* __restrict__ gate_bias, float* __restrict__ agg_parts) {
  __shared__ __align__(16) char klds[32768];   // 32 x 1KB QK A-frag blocks (128 j)
  __shared__ __align__(16) char mlds[32768];   // 32 x 1KB PV A-frag blocks (128 j)
  int t = threadIdx.x, l = t & 63, w = t >> 6;
  int li = l & 31, hi = l >> 5;
  int ig = w & 3, hg = w >> 2;
  int lin = blockIdx.x + blockIdx.y * 64;            // grid (64,8) -> 512
  int nlin = (lin & 7) * 64 + (lin >> 3);            // XCD c owns by = c
  int bx = nlin & 63, by = nlin >> 6;
  int i0 = bx * 128;
  int jbase = by * 1024;
  float gb = gate_bias[0];

  int irow = i0 + ig * 32 + li;
  short8 qf[8];
#pragma unroll
  for (int kc16 = 0; kc16 < 8; ++kc16)
    qf[kc16] = *(const short8*)(q_bf + (size_t)irow * HID + kc16 * 16 + hi * 8);

  const float* arow = adj + (size_t)irow * NN;   // lane's own adjacency row

  const char* kread = klds + l * 16;
  const char* mread = mlds + l * 16;

  f32x16 acc[2];
#pragma unroll
  for (int ht = 0; ht < 2; ++ht)
#pragma unroll
    for (int r = 0; r < 16; ++r) acc[ht][r] = 0.f;

  for (int jt = 0; jt < 8; ++jt) {
    int j0 = jbase + jt * 128;
    __syncthreads();  // all waves done reading tile jt-1
    // stage k,m 128-j tiles (contiguous fragment-major 32 KB each)
    {
      const unsigned short* ksrc = k_bf + (size_t)j0 * 128;
      const unsigned short* msrc = m_t + (size_t)j0 * 128;
#pragma unroll
      for (int p = 0; p < 4; ++p)
        async16(ksrc + (size_t)(p * 512 + t) * 8, klds + p * 8192 + w * 1024);
#pragma unroll
      for (int p = 0; p < 4; ++p)
        async16(msrc + (size_t)(p * 512 + t) * 8, mlds + p * 8192 + w * 1024);
    }
    __syncthreads();  // klds/mlds ready

#pragma unroll
    for (int strip = 0; strip < 4; ++strip) {
      // adj quarter-tile -> regs (issued before QK; QK covers latency)
      f32x4 adjv[4];
#pragma unroll
      for (int q2 = 0; q2 < 4; ++q2)
        adjv[q2] = *(const f32x4*)(arow + j0 + strip * 32 + q2 * 8 + hi * 4);
      // S^T = K @ Q^T : lane -> (i = li, j = j32 + (r&3)+8*(r>>2)+4*hi)
      f32x16 s;
#pragma unroll
      for (int r = 0; r < 16; ++r) s[r] = 0.f;
#pragma unroll
      for (int kc16 = 0; kc16 < 8; ++kc16) {
        const short8 kf = *(const short8*)(kread + strip * 8192 + kc16 * 1024);
        s = __builtin_amdgcn_mfma_f32_32x32x16_bf16(kf, qf[kc16], s, 0, 0, 0);
      }
      // gate in place
#pragma unroll
      for (int r = 0; r < 16; ++r) {
        float x = fmaf(s[r], SCALE, gb);
        float e = __expf(-x);
        s[r] = adjv[r >> 2][r & 3] * __builtin_amdgcn_rcpf(1.0f + e);
      }
      // two K=16 chunks of PV; B-frag via cvt_pk + permlane32_swap
#pragma unroll
      for (int kc = 0; kc < 2; ++kc) {
        unsigned int r0 = cvtpk(s[kc * 8 + 0], s[kc * 8 + 1]);
        unsigned int r1 = cvtpk(s[kc * 8 + 2], s[kc * 8 + 3]);
        unsigned int r2 = cvtpk(s[kc * 8 + 4], s[kc * 8 + 5]);
        unsigned int r3 = cvtpk(s[kc * 8 + 6], s[kc * 8 + 7]);
        asm volatile("v_permlane32_swap_b32 %0, %1" : "+v"(r0), "+v"(r2));
        asm volatile("v_permlane32_swap_b32 %0, %1" : "+v"(r1), "+v"(r3));
        const short8 gf = __builtin_bit_cast(short8, (u32x4){r0, r1, r2, r3});
        int jblk = (strip * 2 + kc) * 4096;
#pragma unroll
        for (int ht = 0; ht < 2; ++ht) {
          const short8 mf =
              *(const short8*)(mread + jblk + (hg * 2 + ht) * 1024);
          acc[ht] = __builtin_amdgcn_mfma_f32_32x32x16_bf16(mf, gf, acc[ht], 0, 0, 0);
        }
      }
    }
  }
  // write aggT[h][i] (lanes 0-31 -> consecutive i: coalesced)
  float* part = agg_parts + (size_t)by * HID * NN;
#pragma unroll
  for (int ht = 0; ht < 2; ++ht)
#pragma unroll
    for (int r = 0; r < 16; ++r) {
      int h = (hg * 2 + ht) * 32 + (r & 3) + 8 * (r >> 2) + 4 * hi;
      part[(size_t)h * NN + i0 + ig * 32 + li] = acc[ht][r];
    }
}

// ---------------- Kernel C: update GEMM + ReLU + LayerNorm ----------------
// 256 blocks x 32 i-rows x 128 thr (R17 regrid win: full-GPU partial-sum).
__global__ __launch_bounds__(128) void kc(
    const unsigned short* __restrict__ nf_bf, const float* __restrict__ agg_parts,
    const unsigned short* __restrict__ w_t, const float* __restrict__ upd_b,
    const float* __restrict__ gamma, const float* __restrict__ beta,
    float* __restrict__ out) {
  __shared__ __align__(16) unsigned short aggl[32][136];
  int t = threadIdx.x, l = t & 63, w = t >> 6;   // w in {0,1}
  int i0 = blockIdx.x * 32;
  // phase 0: sum 8 aggT partials, transpose -> aggl[i][h] bf16
  {
    const size_t ps = (size_t)HID * NN;
#pragma unroll
    for (int pass = 0; pass < 8; ++pass) {
      int h = pass * 16 + (t >> 3);
      const float* pb = agg_parts + (size_t)h * NN + i0 + (t & 7) * 4;
      f32x4 s = (f32x4){0.f, 0.f, 0.f, 0.f};
#pragma unroll
      for (int c = 0; c < 8; ++c) s += *(const f32x4*)(pb + c * ps);
#pragma unroll
      for (int e = 0; e < 4; ++e) aggl[(t & 7) * 4 + e][h] = f2bf(s[e]);
    }
  }
  __syncthreads();
  int lr = l & 15, lg = l >> 4;
  int arow = i0 + w * 16 + lr;
  short8 af[12];
#pragma unroll
  for (int kk = 0; kk < 8; ++kk)
    af[kk] = *(const short8*)(nf_bf + (size_t)arow * DIN + kk * 32 + lg * 8);
#pragma unroll
  for (int kk = 8; kk < 12; ++kk)
    af[kk] = *(const short8*)(&aggl[w * 16 + lr][(kk - 8) * 32 + lg * 8]);
  f32x4 acc[8];
#pragma unroll
  for (int nt = 0; nt < 8; ++nt) acc[nt] = (f32x4){0.f, 0.f, 0.f, 0.f};
#pragma unroll
  for (int kk = 0; kk < 12; ++kk)
#pragma unroll
    for (int nt = 0; nt < 8; ++nt) {
      const short8 bf =
          *(const short8*)(w_t + (size_t)(nt * 16 + lr) * 384 + kk * 32 + lg * 8);
      acc[nt] = __builtin_amdgcn_mfma_f32_16x16x32_bf16(af[kk], bf, acc[nt], 0, 0, 0);
    }
  float ub[8], ga[8], be[8];
#pragma unroll
  for (int nt = 0; nt < 8; ++nt) {
    ub[nt] = upd_b[nt * 16 + lr];
    ga[nt] = gamma[nt * 16 + lr];
    be[nt] = beta[nt * 16 + lr];
  }
  float v[8][4], sum[4], sq[4];
#pragma unroll
  for (int reg = 0; reg < 4; ++reg) { sum[reg] = 0.f; sq[reg] = 0.f; }
#pragma unroll
  for (int nt = 0; nt < 8; ++nt)
#pragma unroll
    for (int reg = 0; reg < 4; ++reg) {
      float x = acc[nt][reg] + ub[nt];
      x = fmaxf(x, 0.f);
      v[nt][reg] = x;
      sum[reg] += x;
      sq[reg] = fmaf(x, x, sq[reg]);
    }
#pragma unroll
  for (int reg = 0; reg < 4; ++reg) {
#pragma unroll
    for (int m = 1; m < 16; m <<= 1) {
      sum[reg] += __shfl_xor(sum[reg], m, 16);
      sq[reg] += __shfl_xor(sq[reg], m, 16);
    }
  }
#pragma unroll
  for (int reg = 0; reg < 4; ++reg) {
    float mu = sum[reg] * (1.0f / 128.0f);
    float var = sq[reg] * (1.0f / 128.0f) - mu * mu;
    float rstd = rsqrtf(var + 1e-5f);
    int orow = i0 + w * 16 + lg * 4 + reg;
#pragma unroll
    for (int nt = 0; nt < 8; ++nt) {
      float y = (v[nt][reg] - mu) * rstd * ga[nt] + be[nt];
      out[(size_t)orow * HID + nt * 16 + lr] = y;
    }
  }
}

extern "C" void kernel_launch(void* const* d_in, const int* in_sizes, int n_in,
                              void* d_out, int out_size, void* d_ws, size_t ws_size,
                              hipStream_t stream) {
  const float* nf    = (const float*)d_in[0];
  const float* adj   = (const float*)d_in[1];
  const float* msg_w = (const float*)d_in[2];
  const float* msg_b = (const float*)d_in[3];
  const float* upd_w = (const float*)d_in[4];
  const float* upd_b = (const float*)d_in[5];
  const float* qw    = (const float*)d_in[6];
  const float* kw    = (const float*)d_in[7];
  const float* gbias = (const float*)d_in[8];
  const float* gamma = (const float*)d_in[9];
  const float* beta  = (const float*)d_in[10];
  char* ws = (char*)d_ws;
  unsigned short* q_bf  = (unsigned short*)(ws);              // 2 MB
  unsigned short* k_bf  = (unsigned short*)(ws + 0x200000);   // 2 MB (fragment-major)
  unsigned short* m_t   = (unsigned short*)(ws + 0x400000);   // 2 MB (fragment-major)
  unsigned short* nf_bf = (unsigned short*)(ws + 0x600000);   // 4 MB
  unsigned short* w_t   = (unsigned short*)(ws + 0xA00000);   // 96 KB
  unsigned short* mwT   = (unsigned short*)(ws + 0xA20000);   // 64 KB
  unsigned short* qwT   = (unsigned short*)(ws + 0xA30000);   // 32 KB
  unsigned short* kwT   = (unsigned short*)(ws + 0xA38000);   // 32 KB
  float* agg            = (float*)(ws + 0xA40000);            // 8 x 4 MB (aggT)

  kw0<<<64, 256, 0, stream>>>(msg_w, qw, kw, upd_w, mwT, qwT, kwT, w_t);
  ka<<<256, 256, 0, stream>>>(nf, mwT, msg_b, qwT, kwT, q_bf, k_bf, m_t, nf_bf);
  kb<<<dim3(64, 8), 512, 0, stream>>>(q_bf, k_bf, m_t, adj, gbias, agg);
  kc<<<256, 128, 0, stream>>>(nf_bf, agg, w_t, upd_b, gamma, beta, (float*)d_out);
}

// Round 19
// 128.849 us; speedup vs baseline: 1.0201x; 1.0201x over previous
//
#include <hip/hip_runtime.h>
#include <hip/hip_bf16.h>
#include <stdint.h>

#define NN 8192
#define DIN 256
#define HID 128
#define SCALE 0.08838834764831845f  // 1/(sqrt(128)*1.0)
#define LOG2E 1.4426950408889634f

typedef __attribute__((ext_vector_type(8))) short short8;
typedef __attribute__((ext_vector_type(4))) float f32x4;
typedef __attribute__((ext_vector_type(16))) float f32x16;
typedef __attribute__((ext_vector_type(8))) unsigned short u16x8;
typedef __attribute__((ext_vector_type(4))) unsigned int u32x4;

__device__ __forceinline__ unsigned short f2bf(float f) {
  unsigned int u = __builtin_bit_cast(unsigned int, f);
  u += 0x7FFFu + ((u >> 16) & 1u);   // round-to-nearest-even
  return (unsigned short)(u >> 16);
}

__device__ __forceinline__ unsigned int cvtpk(float lo, float hi) {
  unsigned int r;
  asm("v_cvt_pk_bf16_f32 %0, %1, %2" : "=v"(r) : "v"(lo), "v"(hi));
  return r;
}

__device__ __forceinline__ void async16(const void* g, void* l) {
  __builtin_amdgcn_global_load_lds(
      (const __attribute__((address_space(1))) unsigned int*)g,
      (__attribute__((address_space(3))) unsigned int*)l, 16, 0, 0);
}

// ---------------- Kernel W: weights -> bf16 transposed ----------------
__global__ __launch_bounds__(256) void kw0(
    const float* __restrict__ msg_w, const float* __restrict__ qw,
    const float* __restrict__ kw, const float* __restrict__ upd_w,
    unsigned short* __restrict__ mwT, unsigned short* __restrict__ qwT,
    unsigned short* __restrict__ kwT, unsigned short* __restrict__ w_t) {
  int idx0 = blockIdx.x * 1792 + threadIdx.x;
#pragma unroll
  for (int it = 0; it < 7; ++it) {
    int idx = idx0 + it * 256;
    if (idx < 32768) {                       // mwT
      int h = idx >> 8, j = idx & 255;
      mwT[idx] = f2bf(msg_w[j * HID + h]);
    } else if (idx < 49152) {                // qwT
      int r = idx - 32768, h = r >> 7, j = r & 127;
      qwT[r] = f2bf(qw[j * HID + h]);
    } else if (idx < 65536) {                // kwT
      int r = idx - 49152, h = r >> 7, j = r & 127;
      kwT[r] = f2bf(kw[j * HID + h]);
    } else {                                 // w_t
      int r = idx - 65536, h = r / 384, j = r % 384;
      w_t[r] = f2bf(upd_w[j * HID + h]);
    }
  }
}

// ---------------- Kernel A: messages, q, k via MFMA ----------------
// k_bf fragment-major: element k[j][kd] ->
//   ((j>>5)*8 + (kd>>4))*512 + (((kd>>3)&1)*32 + (j&31))*8 + (kd&7)
// m_t  fragment-major: element mT[h][j] ->
//   ((j>>4)*4 + (h>>5))*512 + (((j>>3)&1)*32 + (h&31))*8 + (j&7)
__global__ __launch_bounds__(256) void ka(
    const float* __restrict__ nf, const unsigned short* __restrict__ mwT,
    const float* __restrict__ msg_b, const unsigned short* __restrict__ qwT,
    const unsigned short* __restrict__ kwT, unsigned short* __restrict__ q_bf,
    unsigned short* __restrict__ k_bf, unsigned short* __restrict__ m_t,
    unsigned short* __restrict__ nf_bf) {
  __shared__ __align__(16) unsigned short nfl[32][264];
  __shared__ __align__(16) unsigned short ml[32][136];
  int t = threadIdx.x, l = t & 63, w = t >> 6;
  int lr = l & 15, lg = l >> 4;
  int i0 = blockIdx.x * 32;
  {
    int row = t >> 3, c0 = (t & 7) * 32;
    const float* src = nf + (size_t)(i0 + row) * DIN + c0;
    unsigned short* gdst = nf_bf + (size_t)(i0 + row) * DIN + c0;
#pragma unroll
    for (int v = 0; v < 4; ++v) {
      f32x4 a = *(const f32x4*)(src + v * 8);
      f32x4 b = *(const f32x4*)(src + v * 8 + 4);
      u16x8 o;
#pragma unroll
      for (int e = 0; e < 4; ++e) { o[e] = f2bf(a[e]); o[4 + e] = f2bf(b[e]); }
      *(u16x8*)&nfl[row][c0 + v * 8] = o;
      *(u16x8*)(gdst + v * 8) = o;
    }
  }
  __syncthreads();
  int rl = (w >> 1) * 16;
  int nb = (w & 1) * 4;
  f32x4 macc[4];
#pragma unroll
  for (int nt = 0; nt < 4; ++nt) macc[nt] = (f32x4){0.f, 0.f, 0.f, 0.f};
#pragma unroll
  for (int kk = 0; kk < 8; ++kk) {
    short8 af = *(const short8*)&nfl[rl + lr][kk * 32 + lg * 8];
#pragma unroll
    for (int nt = 0; nt < 4; ++nt) {
      short8 bf = *(const short8*)(mwT + (size_t)((nb + nt) * 16 + lr) * DIN + kk * 32 + lg * 8);
      macc[nt] = __builtin_amdgcn_mfma_f32_16x16x32_bf16(af, bf, macc[nt], 0, 0, 0);
    }
  }
#pragma unroll
  for (int nt = 0; nt < 4; ++nt) {
    int col = (nb + nt) * 16 + lr;
    float bias = msg_b[col];
#pragma unroll
    for (int reg = 0; reg < 4; ++reg)
      ml[rl + lg * 4 + reg][col] = f2bf(macc[nt][reg] + bias);
  }
  __syncthreads();
  // m_t writeout: fragment-major
  {
    int hh = t >> 1;
    int Ibase = (t & 1) * 16;
    int I = i0 + Ibase;   // 16-aligned
    unsigned short* mb =
        m_t + ((size_t)(I >> 4) * 4 + (hh >> 5)) * 512 + (hh & 31) * 8;
    u16x8 o0, o1;
#pragma unroll
    for (int v = 0; v < 8; ++v) {
      o0[v] = ml[Ibase + v][hh];
      o1[v] = ml[Ibase + 8 + v][hh];
    }
    *(u16x8*)(mb) = o0;          // j-bit3 = 0 -> lane 0..31 side
    *(u16x8*)(mb + 256) = o1;    // j-bit3 = 1 -> lane 32..63 side
  }
  f32x4 qacc[4], kacc[4];
#pragma unroll
  for (int nt = 0; nt < 4; ++nt) {
    qacc[nt] = (f32x4){0.f, 0.f, 0.f, 0.f};
    kacc[nt] = (f32x4){0.f, 0.f, 0.f, 0.f};
  }
#pragma unroll
  for (int kk = 0; kk < 4; ++kk) {
    short8 af = *(const short8*)&ml[rl + lr][kk * 32 + lg * 8];
#pragma unroll
    for (int nt = 0; nt < 4; ++nt) {
      short8 bq = *(const short8*)(qwT + (size_t)((nb + nt) * 16 + lr) * HID + kk * 32 + lg * 8);
      short8 bk = *(const short8*)(kwT + (size_t)((nb + nt) * 16 + lr) * HID + kk * 32 + lg * 8);
      qacc[nt] = __builtin_amdgcn_mfma_f32_16x16x32_bf16(af, bq, qacc[nt], 0, 0, 0);
      kacc[nt] = __builtin_amdgcn_mfma_f32_16x16x32_bf16(af, bk, kacc[nt], 0, 0, 0);
    }
  }
#pragma unroll
  for (int nt = 0; nt < 4; ++nt) {
    int col = (nb + nt) * 16 + lr;        // kd for k, h for q
#pragma unroll
    for (int reg = 0; reg < 4; ++reg) {
      int row = i0 + rl + lg * 4 + reg;   // node index
      q_bf[(size_t)row * HID + col] = f2bf(qacc[nt][reg]);
      size_t ko = ((size_t)(row >> 5) * 8 + (col >> 4)) * 512 +
                  (((col >> 3) & 1) * 32 + (row & 31)) * 8 + (col & 7);
      k_bf[ko] = f2bf(kacc[nt][reg]);
    }
  }
}

// ---------------- Kernel B: fused gate + aggregate (R17 structure) ----------------
// 64-j staging (R17 champion geometry). ONE change vs R17: log2e folded into
// the gate's scale/bias so sigmoid = rcp(1 + exp2(fma(s,SCALE2,gb2))) -- one
// fewer VALU op per gate element (the compiler's __expf emits v_mul+v_exp).
__global__ __launch_bounds__(512, 4) void kb(
    const unsigned short* __restrict__ q_bf, const unsigned short* __restrict__ k_bf,
    const unsigned short* __restrict__ m_t, const float* __restrict__ adj,
    const float* __restrict__ gate_bias, float* __restrict__ agg_parts) {
  __shared__ __align__(16) char klds[16384];   // 16 x 1KB QK A-frag blocks (64 j)
  __shared__ __align__(16) char mlds[16384];   // 16 x 1KB PV A-frag blocks (64 j)
  int t = threadIdx.x, l = t & 63, w = t >> 6;
  int li = l & 31, hi = l >> 5;
  int ig = w & 3, hg = w >> 2;
  int lin = blockIdx.x + blockIdx.y * 64;            // grid (64,8) -> 512
  int nlin = (lin & 7) * 64 + (lin >> 3);            // XCD c owns by = c
  int bx = nlin & 63, by = nlin >> 6;
  int i0 = bx * 128;
  int jbase = by * 1024;
  const float SCALE2 = -SCALE * LOG2E;               // compile-time fold
  float gb2 = -gate_bias[0] * LOG2E;                 // runtime scalar fold

  int irow = i0 + ig * 32 + li;
  short8 qf[8];
#pragma unroll
  for (int kc16 = 0; kc16 < 8; ++kc16)
    qf[kc16] = *(const short8*)(q_bf + (size_t)irow * HID + kc16 * 16 + hi * 8);

  const float* arow = adj + (size_t)irow * NN;   // lane's own adjacency row

  const char* kread = klds + l * 16;
  const char* mread = mlds + l * 16;

  f32x16 acc[2];
#pragma unroll
  for (int ht = 0; ht < 2; ++ht)
#pragma unroll
    for (int r = 0; r < 16; ++r) acc[ht][r] = 0.f;

  for (int jt = 0; jt < 16; ++jt) {
    int j0 = jbase + jt * 64;
    __syncthreads();  // all waves done reading tile jt-1
    // stage k,m tiles (contiguous fragment-major 16KB each; 512 thr x 2)
    {
      const unsigned short* ksrc = k_bf + (size_t)j0 * 128;
      const unsigned short* msrc = m_t + (size_t)j0 * 128;
#pragma unroll
      for (int p = 0; p < 2; ++p)
        async16(ksrc + (size_t)(p * 512 + t) * 8, klds + p * 8192 + w * 1024);
#pragma unroll
      for (int p = 0; p < 2; ++p)
        async16(msrc + (size_t)(p * 512 + t) * 8, mlds + p * 8192 + w * 1024);
    }
    __syncthreads();  // klds/mlds ready

#pragma unroll
    for (int jt32 = 0; jt32 < 2; ++jt32) {
      // adj quarter-tile -> regs (issued before QK; QK covers latency)
      f32x4 adjv[4];
#pragma unroll
      for (int q2 = 0; q2 < 4; ++q2)
        adjv[q2] = *(const f32x4*)(arow + j0 + jt32 * 32 + q2 * 8 + hi * 4);
      // S^T = K @ Q^T : lane -> (i = li, j = j32 + (r&3)+8*(r>>2)+4*hi)
      f32x16 s;
#pragma unroll
      for (int r = 0; r < 16; ++r) s[r] = 0.f;
#pragma unroll
      for (int kc16 = 0; kc16 < 8; ++kc16) {
        const short8 kf = *(const short8*)(kread + jt32 * 8192 + kc16 * 1024);
        s = __builtin_amdgcn_mfma_f32_32x32x16_bf16(kf, qf[kc16], s, 0, 0, 0);
      }
      // gate in place: sigmoid via exp2 (log2e pre-folded)
#pragma unroll
      for (int r = 0; r < 16; ++r) {
        float e = __builtin_amdgcn_exp2f(fmaf(s[r], SCALE2, gb2));
        s[r] = adjv[r >> 2][r & 3] * __builtin_amdgcn_rcpf(1.0f + e);
      }
      // two K=16 chunks of PV; B-frag via cvt_pk + permlane32_swap
#pragma unroll
      for (int kc = 0; kc < 2; ++kc) {
        unsigned int r0 = cvtpk(s[kc * 8 + 0], s[kc * 8 + 1]);
        unsigned int r1 = cvtpk(s[kc * 8 + 2], s[kc * 8 + 3]);
        unsigned int r2 = cvtpk(s[kc * 8 + 4], s[kc * 8 + 5]);
        unsigned int r3 = cvtpk(s[kc * 8 + 6], s[kc * 8 + 7]);
        asm volatile("v_permlane32_swap_b32 %0, %1" : "+v"(r0), "+v"(r2));
        asm volatile("v_permlane32_swap_b32 %0, %1" : "+v"(r1), "+v"(r3));
        const short8 gf = __builtin_bit_cast(short8, (u32x4){r0, r1, r2, r3});
        int jblk = (jt32 * 2 + kc) * 4096;
#pragma unroll
        for (int ht = 0; ht < 2; ++ht) {
          const short8 mf =
              *(const short8*)(mread + jblk + (hg * 2 + ht) * 1024);
          acc[ht] = __builtin_amdgcn_mfma_f32_32x32x16_bf16(mf, gf, acc[ht], 0, 0, 0);
        }
      }
    }
  }
  // write aggT[h][i] (lanes 0-31 -> consecutive i: coalesced)
  float* part = agg_parts + (size_t)by * HID * NN;
#pragma unroll
  for (int ht = 0; ht < 2; ++ht)
#pragma unroll
    for (int r = 0; r < 16; ++r) {
      int h = (hg * 2 + ht) * 32 + (r & 3) + 8 * (r >> 2) + 4 * hi;
      part[(size_t)h * NN + i0 + ig * 32 + li] = acc[ht][r];
    }
}

// ---------------- Kernel C: update GEMM + ReLU + LayerNorm ----------------
// 256 blocks x 32 i-rows x 128 thr (R17 regrid win: full-GPU partial-sum).
__global__ __launch_bounds__(128) void kc(
    const unsigned short* __restrict__ nf_bf, const float* __restrict__ agg_parts,
    const unsigned short* __restrict__ w_t, const float* __restrict__ upd_b,
    const float* __restrict__ gamma, const float* __restrict__ beta,
    float* __restrict__ out) {
  __shared__ __align__(16) unsigned short aggl[32][136];
  int t = threadIdx.x, l = t & 63, w = t >> 6;   // w in {0,1}
  int i0 = blockIdx.x * 32;
  // phase 0: sum 8 aggT partials, transpose -> aggl[i][h] bf16
  {
    const size_t ps = (size_t)HID * NN;
#pragma unroll
    for (int pass = 0; pass < 8; ++pass) {
      int h = pass * 16 + (t >> 3);
      const float* pb = agg_parts + (size_t)h * NN + i0 + (t & 7) * 4;
      f32x4 s = (f32x4){0.f, 0.f, 0.f, 0.f};
#pragma unroll
      for (int c = 0; c < 8; ++c) s += *(const f32x4*)(pb + c * ps);
#pragma unroll
      for (int e = 0; e < 4; ++e) aggl[(t & 7) * 4 + e][h] = f2bf(s[e]);
    }
  }
  __syncthreads();
  int lr = l & 15, lg = l >> 4;
  int arow = i0 + w * 16 + lr;
  short8 af[12];
#pragma unroll
  for (int kk = 0; kk < 8; ++kk)
    af[kk] = *(const short8*)(nf_bf + (size_t)arow * DIN + kk * 32 + lg * 8);
#pragma unroll
  for (int kk = 8; kk < 12; ++kk)
    af[kk] = *(const short8*)(&aggl[w * 16 + lr][(kk - 8) * 32 + lg * 8]);
  f32x4 acc[8];
#pragma unroll
  for (int nt = 0; nt < 8; ++nt) acc[nt] = (f32x4){0.f, 0.f, 0.f, 0.f};
#pragma unroll
  for (int kk = 0; kk < 12; ++kk)
#pragma unroll
    for (int nt = 0; nt < 8; ++nt) {
      const short8 bf =
          *(const short8*)(w_t + (size_t)(nt * 16 + lr) * 384 + kk * 32 + lg * 8);
      acc[nt] = __builtin_amdgcn_mfma_f32_16x16x32_bf16(af[kk], bf, acc[nt], 0, 0, 0);
    }
  float ub[8], ga[8], be[8];
#pragma unroll
  for (int nt = 0; nt < 8; ++nt) {
    ub[nt] = upd_b[nt * 16 + lr];
    ga[nt] = gamma[nt * 16 + lr];
    be[nt] = beta[nt * 16 + lr];
  }
  float v[8][4], sum[4], sq[4];
#pragma unroll
  for (int reg = 0; reg < 4; ++reg) { sum[reg] = 0.f; sq[reg] = 0.f; }
#pragma unroll
  for (int nt = 0; nt < 8; ++nt)
#pragma unroll
    for (int reg = 0; reg < 4; ++reg) {
      float x = acc[nt][reg] + ub[nt];
      x = fmaxf(x, 0.f);
      v[nt][reg] = x;
      sum[reg] += x;
      sq[reg] = fmaf(x, x, sq[reg]);
    }
#pragma unroll
  for (int reg = 0; reg < 4; ++reg) {
#pragma unroll
    for (int m = 1; m < 16; m <<= 1) {
      sum[reg] += __shfl_xor(sum[reg], m, 16);
      sq[reg] += __shfl_xor(sq[reg], m, 16);
    }
  }
#pragma unroll
  for (int reg = 0; reg < 4; ++reg) {
    float mu = sum[reg] * (1.0f / 128.0f);
    float var = sq[reg] * (1.0f / 128.0f) - mu * mu;
    float rstd = rsqrtf(var + 1e-5f);
    int orow = i0 + w * 16 + lg * 4 + reg;
#pragma unroll
    for (int nt = 0; nt < 8; ++nt) {
      float y = (v[nt][reg] - mu) * rstd * ga[nt] + be[nt];
      out[(size_t)orow * HID + nt * 16 + lr] = y;
    }
  }
}

extern "C" void kernel_launch(void* const* d_in, const int* in_sizes, int n_in,
                              void* d_out, int out_size, void* d_ws, size_t ws_size,
                              hipStream_t stream) {
  const float* nf    = (const float*)d_in[0];
  const float* adj   = (const float*)d_in[1];
  const float* msg_w = (const float*)d_in[2];
  const float* msg_b = (const float*)d_in[3];
  const float* upd_w = (const float*)d_in[4];
  const float* upd_b = (const float*)d_in[5];
  const float* qw    = (const float*)d_in[6];
  const float* kw    = (const float*)d_in[7];
  const float* gbias = (const float*)d_in[8];
  const float* gamma = (const float*)d_in[9];
  const float* beta  = (const float*)d_in[10];
  char* ws = (char*)d_ws;
  unsigned short* q_bf  = (unsigned short*)(ws);              // 2 MB
  unsigned short* k_bf  = (unsigned short*)(ws + 0x200000);   // 2 MB (fragment-major)
  unsigned short* m_t   = (unsigned short*)(ws + 0x400000);   // 2 MB (fragment-major)
  unsigned short* nf_bf = (unsigned short*)(ws + 0x600000);   // 4 MB
  unsigned short* w_t   = (unsigned short*)(ws + 0xA00000);   // 96 KB
  unsigned short* mwT   = (unsigned short*)(ws + 0xA20000);   // 64 KB
  unsigned short* qwT   = (unsigned short*)(ws + 0xA30000);   // 32 KB
  unsigned short* kwT   = (unsigned short*)(ws + 0xA38000);   // 32 KB
  float* agg            = (float*)(ws + 0xA40000);            // 8 x 4 MB (aggT)

  kw0<<<64, 256, 0, stream>>>(msg_w, qw, kw, upd_w, mwT, qwT, kwT, w_t);
  ka<<<256, 256, 0, stream>>>(nf, mwT, msg_b, qwT, kwT, q_bf, k_bf, m_t, nf_bf);
  kb<<<dim3(64, 8), 512, 0, stream>>>(q_bf, k_bf, m_t, adj, gbias, agg);
  kc<<<256, 128, 0, stream>>>(nf_bf, agg, w_t, upd_b, gamma, beta, (float*)d_out);
}